// Round 4
// baseline (563.783 us; speedup 1.0000x reference)
//
#include <hip/hip_runtime.h>
#include <hip/hip_bf16.h>
#include <stdint.h>

#define N_EXPERTS 8
#define D_MODEL   1024
#define D_FF      4096
#define T_TOKENS  2048
#define MT        256
#define MAXT      16      // sum ceil(c/256) <= 8 + 7
#define BK        64
#define KP        72      // LDS k-stride (shorts): 144B rows, 16B aligned, 2-way banks
#define KSPLIT    4
#define KS2       (D_FF / KSPLIT)   // 1024

typedef __attribute__((ext_vector_type(8))) short bf16x8;
typedef __attribute__((ext_vector_type(4))) float f32x4;

__device__ __forceinline__ short f2bf(float f) {
    union { float f; uint32_t u; } v; v.f = f;
    uint32_t u = v.u;
    return (short)((u + 0x7fffu + ((u >> 16) & 1u)) >> 16);
}

__device__ __forceinline__ uint32_t pack2bf(float a, float b) {
    __hip_bfloat162 h = __float22bfloat162_rn(make_float2(a, b));
    return *(uint32_t*)&h;
}

template<int STRIDE>
__device__ __forceinline__ void ldw16(float v[16], const float* __restrict__ src) {
#pragma unroll
    for (int j = 0; j < 16; ++j) v[j] = src[(size_t)j * STRIDE];
}

__device__ __forceinline__ void stw16(short* dst, const float v[16]) {
    uint4 w0, w1;
    w0.x = pack2bf(v[0], v[1]);  w0.y = pack2bf(v[2], v[3]);
    w0.z = pack2bf(v[4], v[5]);  w0.w = pack2bf(v[6], v[7]);
    w1.x = pack2bf(v[8], v[9]);  w1.y = pack2bf(v[10], v[11]);
    w1.z = pack2bf(v[12], v[13]); w1.w = pack2bf(v[14], v[15]);
    *(uint4*)dst = w0;
    *(uint4*)(dst + 8) = w1;
}

// ---------------- routing: count + scan + tile table (MT=256) ----------------

__global__ void moe_route(const int* __restrict__ idx, int* __restrict__ offsets,
                          int* __restrict__ ntp, int* __restrict__ t_e,
                          int* __restrict__ t_p0, int* __restrict__ t_end) {
    __shared__ int cnt[N_EXPERTS];
    int tid = threadIdx.x;
    if (tid < N_EXPERTS) cnt[tid] = 0;
    __syncthreads();
    for (int t = tid; t < T_TOKENS; t += 256) atomicAdd(&cnt[idx[t]], 1);
    __syncthreads();
    if (tid == 0) {
        int off = 0, nt = 0;
        for (int e = 0; e < N_EXPERTS; ++e) {
            offsets[e] = off;
            int c = cnt[e], end = off + c;
            for (int i = 0; i < c; i += MT) { t_e[nt] = e; t_p0[nt] = off + i; t_end[nt] = end; ++nt; }
            off = end;
        }
        offsets[N_EXPERTS] = off;
        *ntp = nt;
    }
}

// one block per token: claim a permuted row slot, gather+convert x row to bf16
__global__ void moe_gather(const float* __restrict__ x, const int* __restrict__ idx,
                           const int* __restrict__ offsets, int* __restrict__ cursor,
                           int* __restrict__ tok_of_row, short* __restrict__ Xg) {
    __shared__ int sp;
    int t = blockIdx.x;
    if (threadIdx.x == 0) {
        int e = idx[t];
        int p = offsets[e] + atomicAdd(&cursor[e], 1);
        tok_of_row[p] = t;
        sp = p;
    }
    __syncthreads();
    int p = sp;
    const float4* src = (const float4*)(x + (size_t)t * D_MODEL);
    uint2* dst = (uint2*)(Xg + (size_t)p * D_MODEL);
    int i = threadIdx.x;                       // D_MODEL/4 == 256 == blockDim
    float4 v = src[i];
    uint2 o;
    o.x = pack2bf(v.x, v.y);
    o.y = pack2bf(v.z, v.w);
    dst[i] = o;
}

// ---------------- GEMM1: gate/up + SwiGLU -> h (bf16) ----------------
// grid (D_FF/64, MAXT), block 256. Tile M=256 N=64 BK=64, read-once weights.
// Wave w owns rows [64w, 64w+64): 4 m-frags, acc 4x4x2 = 128 VGPRs.

__launch_bounds__(256, 2)
__global__ void moe_gemm1(const float* __restrict__ wg, const float* __restrict__ wu,
                          const short* __restrict__ Xg, short* __restrict__ h,
                          const int* __restrict__ tile_e, const int* __restrict__ tile_p0,
                          const int* __restrict__ tile_end, const int* __restrict__ ntiles) {
    int ti = blockIdx.y;
    if (ti >= *ntiles) return;
    int e = tile_e[ti], p0 = tile_p0[ti], pend = tile_end[ti];
    int n0 = blockIdx.x * 64;

    __shared__ short Bg[2][64][KP];
    __shared__ short Bu[2][64][KP];

    int tid = threadIdx.x;
    int nl = tid & 63, kc = tid >> 6;          // staging: n-lane, k-chunk of 16
    int lane = tid & 63, w = tid >> 6;         // compute: wave id
    int col = lane & 15, quad = lane >> 4;

    const float* wgb = wg + (size_t)e * D_MODEL * D_FF + (size_t)(kc * 16) * D_FF + n0 + nl;
    const float* wub = wu + (size_t)e * D_MODEL * D_FF + (size_t)(kc * 16) * D_FF + n0 + nl;

    const short* ap[4];
#pragma unroll
    for (int m = 0; m < 4; ++m) {
        int row = p0 + w * 64 + m * 16 + col;
        if (row > T_TOKENS - 1) row = T_TOKENS - 1;
        ap[m] = Xg + (size_t)row * D_MODEL + quad * 8;
    }

    f32x4 accg[4][4], accu[4][4];
#pragma unroll
    for (int m = 0; m < 4; ++m)
#pragma unroll
        for (int nf = 0; nf < 4; ++nf) {
            accg[m][nf] = (f32x4){0,0,0,0};
            accu[m][nf] = (f32x4){0,0,0,0};
        }

    {   // prologue: stage k=0
        float g0[16], u0[16];
        ldw16<D_FF>(g0, wgb);
        ldw16<D_FF>(u0, wub);
        stw16(&Bg[0][nl][kc * 16], g0);
        stw16(&Bu[0][nl][kc * 16], u0);
    }
    __syncthreads();

    const int NIT = D_MODEL / BK;   // 16
    int p = 0;
#pragma unroll 1
    for (int it = 0; it < NIT; ++it) {
        int kn = (it + 1 == NIT) ? 0 : (it + 1) * BK;   // wrapped prefetch
        float gn[16], un[16];
        ldw16<D_FF>(gn, wgb + (size_t)kn * D_FF);
        ldw16<D_FF>(un, wub + (size_t)kn * D_FF);
        int kb = it * BK;

#pragma unroll
        for (int kk = 0; kk < 2; ++kk) {
            bf16x8 am[4];
#pragma unroll
            for (int m = 0; m < 4; ++m) am[m] = *(const bf16x8*)(ap[m] + kb + kk * 32);
#pragma unroll
            for (int nf = 0; nf < 4; ++nf) {
                bf16x8 bg = *(const bf16x8*)&Bg[p][nf * 16 + col][kk * 32 + quad * 8];
                bf16x8 bu = *(const bf16x8*)&Bu[p][nf * 16 + col][kk * 32 + quad * 8];
#pragma unroll
                for (int m = 0; m < 4; ++m) {
                    accg[m][nf] = __builtin_amdgcn_mfma_f32_16x16x32_bf16(am[m], bg, accg[m][nf], 0, 0, 0);
                    accu[m][nf] = __builtin_amdgcn_mfma_f32_16x16x32_bf16(am[m], bu, accu[m][nf], 0, 0, 0);
                }
            }
        }

        stw16(&Bg[p ^ 1][nl][kc * 16], gn);
        stw16(&Bu[p ^ 1][nl][kc * 16], un);
        __syncthreads();
        p ^= 1;
    }

    // epilogue: h = silu(gate) * up, masked rows
#pragma unroll
    for (int m = 0; m < 4; ++m) {
#pragma unroll
        for (int r = 0; r < 4; ++r) {
            int mr = p0 + w * 64 + m * 16 + quad * 4 + r;
            if (mr < pend) {
#pragma unroll
                for (int nf = 0; nf < 4; ++nf) {
                    float gv = accg[m][nf][r], uv = accu[m][nf][r];
                    float hv = (gv / (1.f + __expf(-gv))) * uv;
                    h[(size_t)mr * D_FF + n0 + nf * 16 + col] = f2bf(hv);
                }
            }
        }
    }
}

// ---------------- GEMM2: out += h @ Wd (split-K x4, atomic combine) ----------------
// grid (D_MODEL/64, MAXT, KSPLIT), block 256. Tile M=256 N=64, K-slice 1024.

__launch_bounds__(256, 2)
__global__ void moe_gemm2(const float* __restrict__ wd, const short* __restrict__ h,
                          const int* __restrict__ tok_of_row, float* __restrict__ out,
                          const int* __restrict__ tile_e, const int* __restrict__ tile_p0,
                          const int* __restrict__ tile_end, const int* __restrict__ ntiles) {
    int ti = blockIdx.y;
    if (ti >= *ntiles) return;
    int e = tile_e[ti], p0 = tile_p0[ti], pend = tile_end[ti];
    int d0 = blockIdx.x * 64;
    int koff = blockIdx.z * KS2;

    __shared__ short Bd[2][64][KP];

    int tid = threadIdx.x;
    int nl = tid & 63, kc = tid >> 6;
    int lane = tid & 63, w = tid >> 6;
    int col = lane & 15, quad = lane >> 4;

    const float* wb = wd + (size_t)e * D_FF * D_MODEL + (size_t)(koff + kc * 16) * D_MODEL + d0 + nl;

    const short* ap[4];
#pragma unroll
    for (int m = 0; m < 4; ++m) {
        int row = p0 + w * 64 + m * 16 + col;
        if (row > T_TOKENS - 1) row = T_TOKENS - 1;
        ap[m] = h + (size_t)row * D_FF + koff + quad * 8;
    }

    f32x4 acc[4][4];
#pragma unroll
    for (int m = 0; m < 4; ++m)
#pragma unroll
        for (int nf = 0; nf < 4; ++nf) acc[m][nf] = (f32x4){0,0,0,0};

    {
        float w0[16];
        ldw16<D_MODEL>(w0, wb);
        stw16(&Bd[0][nl][kc * 16], w0);
    }
    __syncthreads();

    const int NIT = KS2 / BK;   // 16
    int p = 0;
#pragma unroll 1
    for (int it = 0; it < NIT; ++it) {
        int kn = (it + 1 == NIT) ? 0 : (it + 1) * BK;
        float wn[16];
        ldw16<D_MODEL>(wn, wb + (size_t)kn * D_MODEL);
        int kb = it * BK;

#pragma unroll
        for (int kk = 0; kk < 2; ++kk) {
            bf16x8 am[4];
#pragma unroll
            for (int m = 0; m < 4; ++m) am[m] = *(const bf16x8*)(ap[m] + kb + kk * 32);
#pragma unroll
            for (int nf = 0; nf < 4; ++nf) {
                bf16x8 b = *(const bf16x8*)&Bd[p][nf * 16 + col][kk * 32 + quad * 8];
#pragma unroll
                for (int m = 0; m < 4; ++m)
                    acc[m][nf] = __builtin_amdgcn_mfma_f32_16x16x32_bf16(am[m], b, acc[m][nf], 0, 0, 0);
            }
        }

        stw16(&Bd[p ^ 1][nl][kc * 16], wn);
        __syncthreads();
        p ^= 1;
    }

#pragma unroll
    for (int m = 0; m < 4; ++m) {
#pragma unroll
        for (int r = 0; r < 4; ++r) {
            int mr = p0 + w * 64 + m * 16 + quad * 4 + r;
            if (mr < pend) {
                int t = tok_of_row[mr];
#pragma unroll
                for (int nf = 0; nf < 4; ++nf)
                    atomicAdd(&out[(size_t)t * D_MODEL + d0 + nf * 16 + col], acc[m][nf][r]);
            }
        }
    }
}

// ---------------- launch ----------------

extern "C" void kernel_launch(void* const* d_in, const int* in_sizes, int n_in,
                              void* d_out, int out_size, void* d_ws, size_t ws_size,
                              hipStream_t stream) {
    (void)in_sizes; (void)n_in; (void)ws_size;
    const float* x   = (const float*)d_in[0];
    const int*   idx = (const int*)d_in[1];
    const float* wg  = (const float*)d_in[2];
    const float* wu  = (const float*)d_in[3];
    const float* wd  = (const float*)d_in[4];
    float* out = (float*)d_out;

    int* ws_i       = (int*)d_ws;
    int* cursor     = ws_i;            // 8   (memset to 0)
    int* offsets    = ws_i + 8;        // 9
    int* nt         = ws_i + 20;       // 1
    int* t_e        = ws_i + 32;       // 16
    int* t_p0       = ws_i + 48;       // 16
    int* t_end      = ws_i + 64;       // 16
    int* tok_of_row = ws_i + 128;      // 2048

    short* Xg = (short*)((char*)d_ws + 16384);
    short* h  = (short*)((char*)d_ws + 16384 + (size_t)T_TOKENS * D_MODEL * 2);

    hipMemsetAsync(d_ws, 0, 128, stream);
    hipMemsetAsync(d_out, 0, (size_t)out_size * 4, stream);
    moe_route<<<dim3(1), 256, 0, stream>>>(idx, offsets, nt, t_e, t_p0, t_end);
    moe_gather<<<dim3(T_TOKENS), 256, 0, stream>>>(x, idx, offsets, cursor, tok_of_row, Xg);
    moe_gemm1<<<dim3(D_FF / 64, MAXT), 256, 0, stream>>>(wg, wu, Xg, h,
                                                         t_e, t_p0, t_end, nt);
    moe_gemm2<<<dim3(D_MODEL / 64, MAXT, KSPLIT), 256, 0, stream>>>(wd, h, tok_of_row, out,
                                                                    t_e, t_p0, t_end, nt);
}